// Round 1
// baseline (13280.350 us; speedup 1.0000x reference)
//
#include <hip/hip_runtime.h>
#include <cmath>

namespace {

constexpr int Dm  = 512;
constexpr int Bn  = 32;
constexpr int Lq  = 16;
constexpr int V1  = 8193;
constexpr int DFF = 2048;
constexpr int NL  = 2;

__device__ __forceinline__ float wred(float v) {
#pragma unroll
  for (int off = 32; off; off >>= 1) v += __shfl_down(v, off, 64);
  return v;
}

// --- setup kernels ------------------------------------------------------

__global__ __launch_bounds__(64) void init_buf(int* buf) {
  int b = threadIdx.x;
  if (b < Bn) buf[b] = V1 - 1;  // start token = 8192
}

__global__ __launch_bounds__(512) void src_kernel(const int* __restrict__ meanings,
                                                  const float* __restrict__ emb,
                                                  float* __restrict__ src) {
  int b = blockIdx.x, t = threadIdx.x;
  float s = 0.f;
#pragma unroll
  for (int ty = 0; ty < 8; ++ty) {
    int idx = meanings[b * 8 + ty] + ty * 32;
    s += emb[(size_t)idx * Dm + t];
  }
  src[b * Dm + t] = s;
}

// --- generic batched matvec: y[b,n] = bias[n] + sum_k x[b,k]*W[n,k] -----
// grid: (ceil(N/4), B), block 256 (4 waves, one output row per wave)

__global__ __launch_bounds__(256) void matvec(const float* __restrict__ x, int xstride,
                                              const float* __restrict__ W,
                                              const float* __restrict__ bias,
                                              float* __restrict__ y, long long ystride,
                                              int N, int K, int relu) {
  int b = blockIdx.y;
  int wave = threadIdx.x >> 6, lane = threadIdx.x & 63;
  int n = blockIdx.x * 4 + wave;
  if (n >= N) return;
  const float* xr = x + (size_t)b * xstride;
  const float* wr = W + (size_t)n * K;
  float acc = 0.f;
  for (int k = lane * 4; k < K; k += 256) {
    float4 w4 = *(const float4*)(wr + k);
    float4 x4 = *(const float4*)(xr + k);
    acc += w4.x * x4.x + w4.y * x4.y + w4.z * x4.z + w4.w * x4.w;
  }
  acc = wred(acc);
  if (lane == 0) {
    float r = acc + bias[n];
    if (relu) r = fmaxf(r, 0.f);
    y[(size_t)b * ystride + n] = r;
  }
}

// --- QKV with routing: q -> q buffer, k/v -> cache slots ----------------
// grid: (384, B), block 256

__global__ __launch_bounds__(256) void qkv_kernel(const float* __restrict__ x,
                                                  const float* __restrict__ W,
                                                  const float* __restrict__ bias,
                                                  float* __restrict__ q,
                                                  float* __restrict__ kslot,
                                                  float* __restrict__ vslot) {
  int b = blockIdx.y;
  int wave = threadIdx.x >> 6, lane = threadIdx.x & 63;
  int n = blockIdx.x * 4 + wave;  // 0..1535
  const float* xr = x + (size_t)b * Dm;
  const float* wr = W + (size_t)n * Dm;
  float acc = 0.f;
#pragma unroll
  for (int k = lane * 4; k < Dm; k += 256) {
    float4 w4 = *(const float4*)(wr + k);
    float4 x4 = *(const float4*)(xr + k);
    acc += w4.x * x4.x + w4.y * x4.y + w4.z * x4.z + w4.w * x4.w;
  }
  acc = wred(acc);
  if (lane == 0) {
    float r = acc + bias[n];
    if (n < Dm)            q[b * Dm + n]               = r;
    else if (n < 2 * Dm)   kslot[b * Dm + (n - Dm)]    = r;
    else                   vslot[b * Dm + (n - 2 * Dm)] = r;
  }
}

// --- block-wide LayerNorm over 512 values in LDS ------------------------

__device__ void block_ln(float* s, const float* __restrict__ g,
                         const float* __restrict__ bb, int tid, float* red) {
  float ls = 0.f, lq = 0.f;
  for (int t = tid; t < Dm; t += 256) { float v = s[t]; ls += v; lq += v * v; }
  ls = wred(ls); lq = wred(lq);
  int wave = tid >> 6, lane = tid & 63;
  if (lane == 0) { red[wave] = ls; red[4 + wave] = lq; }
  __syncthreads();
  float sum = red[0] + red[1] + red[2] + red[3];
  float sq  = red[4] + red[5] + red[6] + red[7];
  float mean = sum * (1.f / Dm);
  float var  = sq * (1.f / Dm) - mean * mean;
  float inv  = 1.f / sqrtf(var + 1e-5f);
  __syncthreads();
  for (int t = tid; t < Dm; t += 256) s[t] = (s[t] - mean) * inv * g[t] + bb[t];
}

// --- fused: self-attn (cached K/V) + out proj + LN1 + add-ca + LN2 ------
// grid: B blocks, 256 threads

__global__ __launch_bounds__(256) void attn_ln(const float* __restrict__ q,
    const float* __restrict__ kc, const float* __restrict__ vc,
    const float* __restrict__ Wout, const float* __restrict__ bout,
    const float* __restrict__ ca,
    const float* __restrict__ g1, const float* __restrict__ b1,
    const float* __restrict__ g2, const float* __restrict__ b2,
    float* __restrict__ x, int pos) {
  __shared__ float sQ[Dm], sO[Dm], sR[Dm], sS[Lq], red[8];
  int b = blockIdx.x, tid = threadIdx.x;
  int wave = tid >> 6, lane = tid & 63;
  for (int t = tid; t < Dm; t += 256) sQ[t] = q[b * Dm + t];
  __syncthreads();
  // scores over cached keys 0..pos
  for (int j = wave; j <= pos; j += 4) {
    const float* kr = kc + ((size_t)j * Bn + b) * Dm;
    float acc = 0.f;
#pragma unroll
    for (int k = lane * 4; k < Dm; k += 256) {
      float4 k4 = *(const float4*)(kr + k);
      float4 q4 = *(const float4*)(sQ + k);
      acc += k4.x * q4.x + k4.y * q4.y + k4.z * q4.z + k4.w * q4.w;
    }
    acc = wred(acc);
    if (lane == 0) sS[j] = acc * 0.04419417382415922f;  // 1/sqrt(512)
  }
  __syncthreads();
  if (tid == 0) {
    float m = -1e30f;
    for (int j = 0; j <= pos; ++j) m = fmaxf(m, sS[j]);
    float s = 0.f;
    for (int j = 0; j <= pos; ++j) { float e = expf(sS[j] - m); sS[j] = e; s += e; }
    float inv = 1.f / s;
    for (int j = 0; j <= pos; ++j) sS[j] *= inv;
  }
  __syncthreads();
  // weighted sum of cached V
  for (int t = tid; t < Dm; t += 256) {
    float acc = 0.f;
    for (int j = 0; j <= pos; ++j) acc += sS[j] * vc[((size_t)j * Bn + b) * Dm + t];
    sO[t] = acc;
  }
  __syncthreads();
  // out projection + residual
  for (int m = wave; m < Dm; m += 4) {
    const float* wr = Wout + (size_t)m * Dm;
    float acc = 0.f;
#pragma unroll
    for (int k = lane * 4; k < Dm; k += 256) {
      float4 w4 = *(const float4*)(wr + k);
      float4 o4 = *(const float4*)(sO + k);
      acc += w4.x * o4.x + w4.y * o4.y + w4.z * o4.z + w4.w * o4.w;
    }
    acc = wred(acc);
    if (lane == 0) sR[m] = x[b * Dm + m] + acc + bout[m];
  }
  __syncthreads();
  block_ln(sR, g1, b1, tid, red);
  __syncthreads();
  // cross-attn is constant (memory seq-len == 1 -> softmax == 1): add precomputed
  for (int t = tid; t < Dm; t += 256) sR[t] += ca[b * Dm + t];
  __syncthreads();
  block_ln(sR, g2, b2, tid, red);
  __syncthreads();
  for (int t = tid; t < Dm; t += 256) x[b * Dm + t] = sR[t];
}

// --- fused: FFN second matmul + residual + LN3 --------------------------
// grid: B blocks, 256 threads

__global__ __launch_bounds__(256) void ffn2_ln(const float* __restrict__ h1,
    const float* __restrict__ W2, const float* __restrict__ b2,
    const float* __restrict__ g3, const float* __restrict__ b3,
    float* __restrict__ x) {
  __shared__ float sH[DFF];
  __shared__ float sR[Dm], red[8];
  int b = blockIdx.x, tid = threadIdx.x;
  int wave = tid >> 6, lane = tid & 63;
  for (int t = tid; t < DFF; t += 256) sH[t] = h1[b * DFF + t];
  __syncthreads();
  for (int m = wave; m < Dm; m += 4) {
    const float* wr = W2 + (size_t)m * DFF;
    float acc = 0.f;
#pragma unroll
    for (int k = lane * 4; k < DFF; k += 256) {
      float4 w4 = *(const float4*)(wr + k);
      float4 h4 = *(const float4*)(sH + k);
      acc += w4.x * h4.x + w4.y * h4.y + w4.z * h4.z + w4.w * h4.w;
    }
    acc = wred(acc);
    if (lane == 0) sR[m] = x[b * Dm + m] + acc + b2[m];
  }
  __syncthreads();
  block_ln(sR, g3, b3, tid, red);
  __syncthreads();
  for (int t = tid; t < Dm; t += 256) x[b * Dm + t] = sR[t];
}

// --- token embedding + sinusoidal PE ------------------------------------

__global__ __launch_bounds__(512) void embed(const int* __restrict__ buf,
                                             const float* __restrict__ v2e,
                                             float* __restrict__ x, int i) {
  int b = blockIdx.x, t = threadIdx.x;
  int tok = buf[i * Bn + b];
  int j2 = (t >> 1) * 2;
  float div = expf((float)j2 * (-9.210340371976184f / 512.0f));
  float ang = (float)i * div;
  float pe = (t & 1) ? cosf(ang) : sinf(ang);
  x[b * Dm + t] = v2e[(size_t)tok * Dm + t] + pe;
}

// --- argmax over logits row; write token (as float) and feed back -------
// grid: B blocks, 256 threads

__global__ __launch_bounds__(256) void argmax_kernel(const float* __restrict__ logits,
                                                     int* __restrict__ buf,
                                                     float* __restrict__ outToks, int i) {
  int b = blockIdx.x, tid = threadIdx.x;
  const float* row = logits + (size_t)(i * Bn + b) * V1;
  float best = -1e30f; int bi = V1;
  for (int v = tid; v < V1; v += 256) {
    float val = row[v];
    if (val > best) { best = val; bi = v; }  // strided ascending: first-max kept
  }
  __shared__ float sv[256];
  __shared__ int   si[256];
  sv[tid] = best; si[tid] = bi;
  __syncthreads();
  for (int off = 128; off > 0; off >>= 1) {
    if (tid < off) {
      float v2 = sv[tid + off]; int i2 = si[tid + off];
      if (v2 > sv[tid] || (v2 == sv[tid] && i2 < si[tid])) { sv[tid] = v2; si[tid] = i2; }
    }
    __syncthreads();
  }
  if (tid == 0) {
    buf[(i + 1) * Bn + b] = si[0];
    outToks[i * Bn + b] = (float)si[0];
  }
}

}  // namespace

extern "C" void kernel_launch(void* const* d_in, const int* in_sizes, int n_in,
                              void* d_out, int out_size, void* d_ws, size_t ws_size,
                              hipStream_t stream) {
  (void)in_sizes; (void)n_in; (void)out_size; (void)ws_size;
  const int*   meanings  = (const int*)d_in[0];
  const float* emb_table = (const float*)d_in[1];
  const float* v2e_w     = (const float*)d_in[2];
  const float* e2v_w     = (const float*)d_in[3];
  const float* e2v_b     = (const float*)d_in[4];
  const float* sa_qkv_w  = (const float*)d_in[5];
  const float* sa_qkv_b  = (const float*)d_in[6];
  const float* sa_out_w  = (const float*)d_in[7];
  const float* sa_out_b  = (const float*)d_in[8];
  const float* ca_qkv_w  = (const float*)d_in[9];
  const float* ca_qkv_b  = (const float*)d_in[10];
  const float* ca_out_w  = (const float*)d_in[11];
  const float* ca_out_b  = (const float*)d_in[12];
  const float* ffn_w1    = (const float*)d_in[13];
  const float* ffn_b1    = (const float*)d_in[14];
  const float* ffn_w2    = (const float*)d_in[15];
  const float* ffn_b2    = (const float*)d_in[16];
  const float* ln1_g     = (const float*)d_in[17];
  const float* ln1_b     = (const float*)d_in[18];
  const float* ln2_g     = (const float*)d_in[19];
  const float* ln2_b     = (const float*)d_in[20];
  const float* ln3_g     = (const float*)d_in[21];
  const float* ln3_b     = (const float*)d_in[22];

  float* out = (float*)d_out;            // toks [16,32] then logits [16,32,8193]
  float* outLogits = out + Lq * Bn;

  char* ws = (char*)d_ws;
  int*   buf    = (int*)ws;                          // 17*32 ints
  float* src    = (float*)(ws + 4096);               // [32,512]
  float* tmpv   = src + Bn * Dm;                     // [32,512]
  float* caC    = tmpv + Bn * Dm;                    // [2,32,512]
  float* x      = caC + NL * Bn * Dm;                // [32,512]
  float* q      = x + Bn * Dm;                       // [32,512]
  float* h1     = q + Bn * Dm;                       // [32,2048]
  float* kcache = h1 + Bn * DFF;                     // [2,16,32,512]
  float* vcache = kcache + (size_t)NL * Lq * Bn * Dm;

  init_buf<<<1, 64, 0, stream>>>(buf);
  src_kernel<<<Bn, Dm, 0, stream>>>(meanings, emb_table, src);

  // Precompute per-layer cross-attn constant: out_w @ (Wv src + bv) + out_b
  for (int l = 0; l < NL; ++l) {
    matvec<<<dim3(128, Bn), 256, 0, stream>>>(src, Dm,
        ca_qkv_w + (size_t)l * 3 * Dm * Dm + (size_t)2 * Dm * Dm,
        ca_qkv_b + l * 3 * Dm + 2 * Dm, tmpv, Dm, Dm, Dm, 0);
    matvec<<<dim3(128, Bn), 256, 0, stream>>>(tmpv, Dm,
        ca_out_w + (size_t)l * Dm * Dm, ca_out_b + l * Dm,
        caC + (size_t)l * Bn * Dm, Dm, Dm, Dm, 0);
  }

  for (int i = 0; i < Lq; ++i) {
    embed<<<Bn, Dm, 0, stream>>>(buf, v2e_w, x, i);
    for (int l = 0; l < NL; ++l) {
      float* kc = kcache + (size_t)l * Lq * Bn * Dm;
      float* vc = vcache + (size_t)l * Lq * Bn * Dm;
      qkv_kernel<<<dim3(384, Bn), 256, 0, stream>>>(x,
          sa_qkv_w + (size_t)l * 3 * Dm * Dm, sa_qkv_b + l * 3 * Dm,
          q, kc + (size_t)i * Bn * Dm, vc + (size_t)i * Bn * Dm);
      attn_ln<<<Bn, 256, 0, stream>>>(q, kc, vc,
          sa_out_w + (size_t)l * Dm * Dm, sa_out_b + l * Dm,
          caC + (size_t)l * Bn * Dm,
          ln1_g + l * Dm, ln1_b + l * Dm, ln2_g + l * Dm, ln2_b + l * Dm,
          x, i);
      matvec<<<dim3(512, Bn), 256, 0, stream>>>(x, Dm,
          ffn_w1 + (size_t)l * DFF * Dm, ffn_b1 + l * DFF, h1, DFF, DFF, Dm, 1);
      ffn2_ln<<<Bn, 256, 0, stream>>>(h1,
          ffn_w2 + (size_t)l * Dm * DFF, ffn_b2 + l * Dm,
          ln3_g + l * Dm, ln3_b + l * Dm, x);
    }
    matvec<<<dim3((V1 + 3) / 4, Bn), 256, 0, stream>>>(x, Dm, e2v_w, e2v_b,
        outLogits + (size_t)i * Bn * V1, V1, V1, Dm, 0);
    argmax_kernel<<<Bn, 256, 0, stream>>>(outLogits, buf, out, i);
  }
}

// Round 2
// 3267.590 us; speedup vs baseline: 4.0643x; 4.0643x over previous
//
#include <hip/hip_runtime.h>
#include <cmath>

namespace {

constexpr int Dm  = 512;
constexpr int Bn  = 32;
constexpr int Lq  = 16;
constexpr int V1  = 8193;
constexpr int DFF = 2048;
constexpr int NL  = 2;

__device__ __forceinline__ float wred(float v) {
#pragma unroll
  for (int off = 32; off; off >>= 1) v += __shfl_down(v, off, 64);
  return v;
}

// --- setup kernels ------------------------------------------------------

__global__ __launch_bounds__(64) void init_buf(int* buf) {
  int b = threadIdx.x;
  if (b < Bn) buf[b] = V1 - 1;  // start token = 8192
}

__global__ __launch_bounds__(512) void src_kernel(const int* __restrict__ meanings,
                                                  const float* __restrict__ emb,
                                                  float* __restrict__ src) {
  int b = blockIdx.x, t = threadIdx.x;
  float s = 0.f;
#pragma unroll
  for (int ty = 0; ty < 8; ++ty) {
    int idx = meanings[b * 8 + ty] + ty * 32;
    s += emb[(size_t)idx * Dm + t];
  }
  src[b * Dm + t] = s;
}

// --- generic batched matvec: y[b,n] = bias[n] + sum_k x[b,k]*W[n,k] -----
// grid: (ceil(N/4), B), block 256 (4 waves, one output row per wave)

__global__ __launch_bounds__(256) void matvec(const float* __restrict__ x, int xstride,
                                              const float* __restrict__ W,
                                              const float* __restrict__ bias,
                                              float* __restrict__ y, long long ystride,
                                              int N, int K, int relu) {
  int b = blockIdx.y;
  int wave = threadIdx.x >> 6, lane = threadIdx.x & 63;
  int n = blockIdx.x * 4 + wave;
  if (n >= N) return;
  const float* xr = x + (size_t)b * xstride;
  const float* wr = W + (size_t)n * K;
  float acc = 0.f;
  for (int k = lane * 4; k < K; k += 256) {
    float4 w4 = *(const float4*)(wr + k);
    float4 x4 = *(const float4*)(xr + k);
    acc += w4.x * x4.x + w4.y * x4.y + w4.z * x4.z + w4.w * x4.w;
  }
  acc = wred(acc);
  if (lane == 0) {
    float r = acc + bias[n];
    if (relu) r = fmaxf(r, 0.f);
    y[(size_t)b * ystride + n] = r;
  }
}

// --- QKV with routing: q -> q buffer, k/v -> cache slots ----------------
// grid: (384, B), block 256

__global__ __launch_bounds__(256) void qkv_kernel(const float* __restrict__ x,
                                                  const float* __restrict__ W,
                                                  const float* __restrict__ bias,
                                                  float* __restrict__ q,
                                                  float* __restrict__ kslot,
                                                  float* __restrict__ vslot) {
  int b = blockIdx.y;
  int wave = threadIdx.x >> 6, lane = threadIdx.x & 63;
  int n = blockIdx.x * 4 + wave;  // 0..1535
  const float* xr = x + (size_t)b * Dm;
  const float* wr = W + (size_t)n * Dm;
  float acc = 0.f;
#pragma unroll
  for (int k = lane * 4; k < Dm; k += 256) {
    float4 w4 = *(const float4*)(wr + k);
    float4 x4 = *(const float4*)(xr + k);
    acc += w4.x * x4.x + w4.y * x4.y + w4.z * x4.z + w4.w * x4.w;
  }
  acc = wred(acc);
  if (lane == 0) {
    float r = acc + bias[n];
    if (n < Dm)            q[b * Dm + n]               = r;
    else if (n < 2 * Dm)   kslot[b * Dm + (n - Dm)]    = r;
    else                   vslot[b * Dm + (n - 2 * Dm)] = r;
  }
}

// --- block-wide LayerNorm over 512 values in LDS ------------------------

__device__ void block_ln(float* s, const float* __restrict__ g,
                         const float* __restrict__ bb, int tid, float* red) {
  float ls = 0.f, lq = 0.f;
  for (int t = tid; t < Dm; t += 256) { float v = s[t]; ls += v; lq += v * v; }
  ls = wred(ls); lq = wred(lq);
  int wave = tid >> 6, lane = tid & 63;
  if (lane == 0) { red[wave] = ls; red[4 + wave] = lq; }
  __syncthreads();
  float sum = red[0] + red[1] + red[2] + red[3];
  float sq  = red[4] + red[5] + red[6] + red[7];
  float mean = sum * (1.f / Dm);
  float var  = sq * (1.f / Dm) - mean * mean;
  float inv  = 1.f / sqrtf(var + 1e-5f);
  __syncthreads();
  for (int t = tid; t < Dm; t += 256) s[t] = (s[t] - mean) * inv * g[t] + bb[t];
}

// --- attention core: scores + softmax + weighted-V (tiny, 32 blocks) ----
// grid: B blocks, 256 threads

__global__ __launch_bounds__(256) void attn_core(const float* __restrict__ q,
    const float* __restrict__ kc, const float* __restrict__ vc,
    float* __restrict__ aout, int pos) {
  __shared__ float sQ[Dm], sS[Lq];
  int b = blockIdx.x, tid = threadIdx.x;
  int wave = tid >> 6, lane = tid & 63;
  for (int t = tid; t < Dm; t += 256) sQ[t] = q[b * Dm + t];
  __syncthreads();
  for (int j = wave; j <= pos; j += 4) {
    const float* kr = kc + ((size_t)j * Bn + b) * Dm;
    float acc = 0.f;
#pragma unroll
    for (int k = lane * 4; k < Dm; k += 256) {
      float4 k4 = *(const float4*)(kr + k);
      float4 q4 = *(const float4*)(sQ + k);
      acc += k4.x * q4.x + k4.y * q4.y + k4.z * q4.z + k4.w * q4.w;
    }
    acc = wred(acc);
    if (lane == 0) sS[j] = acc * 0.04419417382415922f;  // 1/sqrt(512)
  }
  __syncthreads();
  if (tid == 0) {
    float m = -1e30f;
    for (int j = 0; j <= pos; ++j) m = fmaxf(m, sS[j]);
    float s = 0.f;
    for (int j = 0; j <= pos; ++j) { float e = expf(sS[j] - m); sS[j] = e; s += e; }
    float inv = 1.f / s;
    for (int j = 0; j <= pos; ++j) sS[j] *= inv;
  }
  __syncthreads();
  for (int t = tid; t < Dm; t += 256) {
    float acc = 0.f;
    for (int j = 0; j <= pos; ++j) acc += sS[j] * vc[((size_t)j * Bn + b) * Dm + t];
    aout[b * Dm + t] = acc;
  }
}

// --- residual + LN1 + add-ca + LN2 (elementwise, 32 blocks) -------------

__global__ __launch_bounds__(256) void ln12_kernel(const float* __restrict__ tmp,
    const float* __restrict__ ca,
    const float* __restrict__ g1, const float* __restrict__ b1,
    const float* __restrict__ g2, const float* __restrict__ b2,
    float* __restrict__ x) {
  __shared__ float sR[Dm], red[8];
  int b = blockIdx.x, tid = threadIdx.x;
  for (int t = tid; t < Dm; t += 256) sR[t] = x[b * Dm + t] + tmp[b * Dm + t];
  __syncthreads();
  block_ln(sR, g1, b1, tid, red);
  __syncthreads();
  for (int t = tid; t < Dm; t += 256) sR[t] += ca[b * Dm + t];
  __syncthreads();
  block_ln(sR, g2, b2, tid, red);
  __syncthreads();
  for (int t = tid; t < Dm; t += 256) x[b * Dm + t] = sR[t];
}

// --- residual + LN3 (elementwise, 32 blocks) ----------------------------

__global__ __launch_bounds__(256) void ln3_kernel(const float* __restrict__ tmp,
    const float* __restrict__ g3, const float* __restrict__ b3,
    float* __restrict__ x) {
  __shared__ float sR[Dm], red[8];
  int b = blockIdx.x, tid = threadIdx.x;
  for (int t = tid; t < Dm; t += 256) sR[t] = x[b * Dm + t] + tmp[b * Dm + t];
  __syncthreads();
  block_ln(sR, g3, b3, tid, red);
  __syncthreads();
  for (int t = tid; t < Dm; t += 256) x[b * Dm + t] = sR[t];
}

// --- token embedding + sinusoidal PE ------------------------------------

__global__ __launch_bounds__(512) void embed(const int* __restrict__ buf,
                                             const float* __restrict__ v2e,
                                             float* __restrict__ x, int i) {
  int b = blockIdx.x, t = threadIdx.x;
  int tok = buf[i * Bn + b];
  int j2 = (t >> 1) * 2;
  float div = expf((float)j2 * (-9.210340371976184f / 512.0f));
  float ang = (float)i * div;
  float pe = (t & 1) ? cosf(ang) : sinf(ang);
  x[b * Dm + t] = v2e[(size_t)tok * Dm + t] + pe;
}

// --- argmax over logits row; write token (as float) and feed back -------
// grid: B blocks, 256 threads

__global__ __launch_bounds__(256) void argmax_kernel(const float* __restrict__ logits,
                                                     int* __restrict__ buf,
                                                     float* __restrict__ outToks, int i) {
  int b = blockIdx.x, tid = threadIdx.x;
  const float* row = logits + (size_t)(i * Bn + b) * V1;
  float best = -1e30f; int bi = V1;
  for (int v = tid; v < V1; v += 256) {
    float val = row[v];
    if (val > best) { best = val; bi = v; }  // strided ascending: first-max kept
  }
  __shared__ float sv[256];
  __shared__ int   si[256];
  sv[tid] = best; si[tid] = bi;
  __syncthreads();
  for (int off = 128; off > 0; off >>= 1) {
    if (tid < off) {
      float v2 = sv[tid + off]; int i2 = si[tid + off];
      if (v2 > sv[tid] || (v2 == sv[tid] && i2 < si[tid])) { sv[tid] = v2; si[tid] = i2; }
    }
    __syncthreads();
  }
  if (tid == 0) {
    buf[(i + 1) * Bn + b] = si[0];
    outToks[i * Bn + b] = (float)si[0];
  }
}

}  // namespace

extern "C" void kernel_launch(void* const* d_in, const int* in_sizes, int n_in,
                              void* d_out, int out_size, void* d_ws, size_t ws_size,
                              hipStream_t stream) {
  (void)in_sizes; (void)n_in; (void)out_size; (void)ws_size;
  const int*   meanings  = (const int*)d_in[0];
  const float* emb_table = (const float*)d_in[1];
  const float* v2e_w     = (const float*)d_in[2];
  const float* e2v_w     = (const float*)d_in[3];
  const float* e2v_b     = (const float*)d_in[4];
  const float* sa_qkv_w  = (const float*)d_in[5];
  const float* sa_qkv_b  = (const float*)d_in[6];
  const float* sa_out_w  = (const float*)d_in[7];
  const float* sa_out_b  = (const float*)d_in[8];
  const float* ca_qkv_w  = (const float*)d_in[9];
  const float* ca_qkv_b  = (const float*)d_in[10];
  const float* ca_out_w  = (const float*)d_in[11];
  const float* ca_out_b  = (const float*)d_in[12];
  const float* ffn_w1    = (const float*)d_in[13];
  const float* ffn_b1    = (const float*)d_in[14];
  const float* ffn_w2    = (const float*)d_in[15];
  const float* ffn_b2    = (const float*)d_in[16];
  const float* ln1_g     = (const float*)d_in[17];
  const float* ln1_b     = (const float*)d_in[18];
  const float* ln2_g     = (const float*)d_in[19];
  const float* ln2_b     = (const float*)d_in[20];
  const float* ln3_g     = (const float*)d_in[21];
  const float* ln3_b     = (const float*)d_in[22];

  float* out = (float*)d_out;            // toks [16,32] then logits [16,32,8193]
  float* outLogits = out + Lq * Bn;

  char* ws = (char*)d_ws;
  int*   buf    = (int*)ws;                          // 17*32 ints
  float* src    = (float*)(ws + 4096);               // [32,512]
  float* tmpv   = src + Bn * Dm;                     // [32,512]
  float* caC    = tmpv + Bn * Dm;                    // [2,32,512]
  float* x      = caC + NL * Bn * Dm;                // [32,512]
  float* q      = x + Bn * Dm;                       // [32,512]
  float* aout   = q + Bn * Dm;                       // [32,512]
  float* h1     = aout + Bn * Dm;                    // [32,2048]
  float* kcache = h1 + Bn * DFF;                     // [2,16,32,512]
  float* vcache = kcache + (size_t)NL * Lq * Bn * Dm;

  init_buf<<<1, 64, 0, stream>>>(buf);
  src_kernel<<<Bn, Dm, 0, stream>>>(meanings, emb_table, src);

  // Precompute per-layer cross-attn constant: out_w @ (Wv src + bv) + out_b
  // (memory seq-len == 1 -> softmax over one key == 1; independent of query)
  for (int l = 0; l < NL; ++l) {
    matvec<<<dim3(128, Bn), 256, 0, stream>>>(src, Dm,
        ca_qkv_w + (size_t)l * 3 * Dm * Dm + (size_t)2 * Dm * Dm,
        ca_qkv_b + l * 3 * Dm + 2 * Dm, tmpv, Dm, Dm, Dm, 0);
    matvec<<<dim3(128, Bn), 256, 0, stream>>>(tmpv, Dm,
        ca_out_w + (size_t)l * Dm * Dm, ca_out_b + l * Dm,
        caC + (size_t)l * Bn * Dm, Dm, Dm, Dm, 0);
  }

  for (int i = 0; i < Lq; ++i) {
    embed<<<Bn, Dm, 0, stream>>>(buf, v2e_w, x, i);
    for (int l = 0; l < NL; ++l) {
      float* kc = kcache + (size_t)l * Lq * Bn * Dm;
      float* vc = vcache + (size_t)l * Lq * Bn * Dm;
      qkv_kernel<<<dim3(384, Bn), 256, 0, stream>>>(x,
          sa_qkv_w + (size_t)l * 3 * Dm * Dm, sa_qkv_b + l * 3 * Dm,
          q, kc + (size_t)i * Bn * Dm, vc + (size_t)i * Bn * Dm);
      attn_core<<<Bn, 256, 0, stream>>>(q, kc, vc, aout, i);
      matvec<<<dim3(128, Bn), 256, 0, stream>>>(aout, Dm,
          sa_out_w + (size_t)l * Dm * Dm, sa_out_b + l * Dm, tmpv, Dm, Dm, Dm, 0);
      ln12_kernel<<<Bn, 256, 0, stream>>>(tmpv, caC + (size_t)l * Bn * Dm,
          ln1_g + l * Dm, ln1_b + l * Dm, ln2_g + l * Dm, ln2_b + l * Dm, x);
      matvec<<<dim3(512, Bn), 256, 0, stream>>>(x, Dm,
          ffn_w1 + (size_t)l * DFF * Dm, ffn_b1 + l * DFF, h1, DFF, DFF, Dm, 1);
      matvec<<<dim3(128, Bn), 256, 0, stream>>>(h1, DFF,
          ffn_w2 + (size_t)l * Dm * DFF, ffn_b2 + l * Dm, tmpv, Dm, Dm, DFF, 0);
      ln3_kernel<<<Bn, 256, 0, stream>>>(tmpv,
          ln3_g + l * Dm, ln3_b + l * Dm, x);
    }
    matvec<<<dim3((V1 + 3) / 4, Bn), 256, 0, stream>>>(x, Dm, e2v_w, e2v_b,
        outLogits + (size_t)i * Bn * V1, V1, V1, Dm, 0);
    argmax_kernel<<<Bn, 256, 0, stream>>>(outLogits, buf, out, i);
  }
}